// Round 7
// baseline (87.547 us; speedup 1.0000x reference)
//
#include <hip/hip_runtime.h>

// RegistrationLoss: sim = -mean(NCC_9x9x9(warped, fixed)), reg = bending energy of flow,
// total = sim + 0.01*reg. Inputs f32: warped[2,1,128,128,128], fixed same, flow[2,3,128,128,128].
// Output: 3 floats [total, sim, reg].
//
// Round-7 structure:
//   wh_bend (fused, 4096 blocks): blockIdx%4==0 -> ncc_wh wave-work (1024 blocks);
//            else -> bending energy (3072 blocks, grid-stride x4). Bending's BW-bound
//            waves fill ncc_wh's latency stalls on the same CUs.
//   ncc_wh path: double-buffered wave-private zero-padded LDS row (no barriers; step s
//            writes row s+1 to the other slot -> no intra-step ds_write->ds_read dep),
//            5 shifted ds_read_b64 views, W-box, H-box f32 register ring,
//            bufB packed bf16 (42 MB).
//   ncc_d:   D-box (register ring over 16 d-segments) + NCC + block reduce; f32 accum.
// bufB row layout (per (b,d,h), 320 unsigned = 1280 B):
//   [0,128): uint2{bf2(f0), bf2(f1)} per w-pair   [128,256): uint2{bf2(f2), bf2(f3)}
//   [256,320): bf2(f4) dword per w-pair
// Lessons kept: no min-waves launch_bounds (R4: VGPR cap 64 -> spill); no per-LANE
// conditional global loads (R5: exec-mask serialization) — row-validity guards here
// are wave-uniform (h from h0,s only).

#define DIM 128
#define V   4194304L      // 2*128^3
#define NVOL6 12582912L   // 6*128^3

#define ZER2 make_float2(0.f, 0.f)

__device__ __forceinline__ unsigned pack_bf2(float2 v) {
    unsigned ax = __float_as_uint(v.x), ay = __float_as_uint(v.y);
    ax = ax + 0x7fffu + ((ax >> 16) & 1u);      // round-to-nearest-even
    ay = ay + 0x7fffu + ((ay >> 16) & 1u);
    return (ax >> 16) | (ay & 0xffff0000u);
}
__device__ __forceinline__ float2 unpack_bf2(unsigned u) {
    return make_float2(__uint_as_float(u << 16), __uint_as_float(u & 0xffff0000u));
}

__device__ __forceinline__ float wave_block_reduce_partial(float local, float* lds, int t, int nwaves) {
    #pragma unroll
    for (int off = 32; off > 0; off >>= 1) local += __shfl_down(local, off, 64);
    if ((t & 63) == 0) lds[t >> 6] = local;
    __syncthreads();
    float s = 0.f;
    if (t == 0) {
        for (int i = 0; i < nwaves; ++i) s += lds[i];
    }
    return s; // valid on t==0 only
}

// ---------------- Fused kernel: ncc_wh blocks + bending blocks ----------------
__global__ __launch_bounds__(256) void wh_bend(const float* __restrict__ I,
                                               const float* __restrict__ J,
                                               const float* __restrict__ F,
                                               unsigned* __restrict__ bufB,
                                               float* __restrict__ regPartial) {
    __shared__ float smem[4][2][2][136];  // [wave][slot][src][4 pad | 128 | 4 pad]

    const int bt = blockIdx.x & 3;

    if (bt == 0) {
        // ================= ncc_wh path =================
        const int lane = threadIdx.x & 63;
        const int wv   = threadIdx.x >> 6;
        const int wid  = ((blockIdx.x >> 2) << 2) + wv;   // [0, 4096)
        const int e = wid & 15;           // h-chunk
        const int d = (wid >> 4) & 127;
        const int b = wid >> 11;
        const int h0 = e << 3;
        const int w0 = lane << 1;
        const int sliceBase = (b * 128 + d) * 16384;

        // zero the pads of both slots/sources once (lanes 0..3)
        if (lane < 4) {
            #pragma unroll
            for (int sl = 0; sl < 2; ++sl)
                #pragma unroll
                for (int sc = 0; sc < 2; ++sc) {
                    smem[wv][sl][sc][lane] = 0.f;
                    smem[wv][sl][sc][132 + lane] = 0.f;
                }
        }

        float2 win[9][5];
        float2 hs[5];
        #pragma unroll
        for (int f = 0; f < 5; ++f) hs[f] = ZER2;

        // prologue: row h0-4 -> slot 0; prefetch row h0-3
        {
            const int h = h0 - 4;
            float2 ca = ZER2, cb = ZER2;
            if ((unsigned)h < 128u) {     // wave-uniform guard
                ca = *reinterpret_cast<const float2*>(I + sliceBase + h * 128 + w0);
                cb = *reinterpret_cast<const float2*>(J + sliceBase + h * 128 + w0);
            }
            *reinterpret_cast<float2*>(&smem[wv][0][0][4 + w0]) = ca;
            *reinterpret_cast<float2*>(&smem[wv][0][1][4 + w0]) = cb;
        }
        float2 na = ZER2, nb = ZER2;
        {
            const int h = h0 - 3;
            if ((unsigned)h < 128u) {
                na = *reinterpret_cast<const float2*>(I + sliceBase + h * 128 + w0);
                nb = *reinterpret_cast<const float2*>(J + sliceBase + h * 128 + w0);
            }
        }

        #pragma unroll
        for (int s = 0; s < 16; ++s) {
            const int slot = s & 1, nslot = slot ^ 1;
            // stage next row (s+1) into the other slot
            *reinterpret_cast<float2*>(&smem[wv][nslot][0][4 + w0]) = na;
            *reinterpret_cast<float2*>(&smem[wv][nslot][1][4 + w0]) = nb;
            // prefetch row for step s+2
            {
                const int h = h0 - 2 + s;
                if ((unsigned)h < 128u) {
                    na = *reinterpret_cast<const float2*>(I + sliceBase + h * 128 + w0);
                    nb = *reinterpret_cast<const float2*>(J + sliceBase + h * 128 + w0);
                } else {
                    na = ZER2; nb = ZER2;
                }
            }

            // 5 shifted views of current row (written last step, other slot)
            float2 iv[5], jv[5];
            #pragma unroll
            for (int o = 0; o < 5; ++o) {
                iv[o] = *reinterpret_cast<const float2*>(&smem[wv][slot][0][w0 + 2 * o]);
                jv[o] = *reinterpret_cast<const float2*>(&smem[wv][slot][1][w0 + 2 * o]);
            }

            float2 v[5][5];
            #pragma unroll
            for (int o = 0; o < 5; ++o) {
                v[0][o] = iv[o];
                v[1][o] = jv[o];
                v[2][o] = make_float2(iv[o].x * iv[o].x, iv[o].y * iv[o].y);
                v[3][o] = make_float2(jv[o].x * jv[o].x, jv[o].y * jv[o].y);
                v[4][o] = make_float2(iv[o].x * jv[o].x, iv[o].y * jv[o].y);
            }

            #pragma unroll
            for (int f = 0; f < 5; ++f) {
                const float core = v[f][1].x + v[f][1].y + v[f][2].x + v[f][2].y
                                 + v[f][3].x + v[f][3].y;
                float2 wb;
                wb.x = core + v[f][0].x + v[f][0].y + v[f][4].x;   // window w-4..w+4
                wb.y = core + v[f][0].y + v[f][4].x + v[f][4].y;   // window w-3..w+5
                if (s >= 9) { hs[f].x -= win[s % 9][f].x; hs[f].y -= win[s % 9][f].y; }
                hs[f].x += wb.x; hs[f].y += wb.y;
                win[s % 9][f] = wb;
            }

            if (s >= 8) {
                const int h_out = h0 + s - 8;
                unsigned* row = bufB + ((b * 128 + d) * 128 + h_out) * 320;
                const uint2 p01 = make_uint2(pack_bf2(hs[0]), pack_bf2(hs[1]));
                const uint2 p23 = make_uint2(pack_bf2(hs[2]), pack_bf2(hs[3]));
                *reinterpret_cast<uint2*>(row + 2 * lane)       = p01;
                *reinterpret_cast<uint2*>(row + 128 + 2 * lane) = p23;
                row[256 + lane] = pack_bf2(hs[4]);
            }
        }
    } else {
        // ================= bending path =================
        const float invS = 1.0f / 12386304.0f;   // 6*126*128*128  (i==j)
        const float invC = 1.0f / 12289536.0f;   // 6*127*126*128  (i!=j, both orderings)
        const int vb = (blockIdx.x >> 2) * 3 + bt - 1;   // [0, 3072) bijective

        float local = 0.f;
        #pragma unroll
        for (int it = 0; it < 4; ++it) {
            const int tid = (vb + it * 3072) * 256 + threadIdx.x;   // [0, 3145728)
            const long e = (long)tid << 2;                           // element base
            const int r = (int)(e & 2097151);
            const int d = r >> 14;
            const int h = (r >> 7) & 127;
            const int w0 = r & 127;                                  // 0,4,...,124

            const float* p = F + e;
            const int off4 = (w0 < 124) ? 4 : 0;
            const int oD  = (d < 127) ? 16384 : 0;
            const int oD2 = (d < 126) ? 32768 : 0;
            const int oH  = (h < 127) ? 128 : 0;
            const int oH2 = (h < 126) ? 256 : 0;

            const float4 a0  = *reinterpret_cast<const float4*>(p);
            const float2 s45 = *reinterpret_cast<const float2*>(p + off4);
            const float4 aD  = *reinterpret_cast<const float4*>(p + oD);
            const float  sD4 = (p + oD)[off4];
            const float4 aD2 = *reinterpret_cast<const float4*>(p + oD2);
            const float4 aH  = *reinterpret_cast<const float4*>(p + oH);
            const float  sH4 = (p + oH)[off4];
            const float4 aH2 = *reinterpret_cast<const float4*>(p + oH2);
            const float4 aDH = *reinterpret_cast<const float4*>(p + oD + oH);

            const float A0[6] = {a0.x, a0.y, a0.z, a0.w, s45.x, s45.y};
            const float AD[5] = {aD.x, aD.y, aD.z, aD.w, sD4};
            const float AH[5] = {aH.x, aH.y, aH.z, aH.w, sH4};
            const float AD2[4] = {aD2.x, aD2.y, aD2.z, aD2.w};
            const float AH2[4] = {aH2.x, aH2.y, aH2.z, aH2.w};
            const float ADH[4] = {aDH.x, aDH.y, aDH.z, aDH.w};

            const float mD2 = (d < 126) ? invS : 0.f;
            const float mH2 = (h < 126) ? invS : 0.f;
            const float cD  = (d < 126) ? 1.f : 0.f;
            const float cH  = (h < 126) ? 1.f : 0.f;
            const bool  vD  = d < 127, vH = h < 127;

            #pragma unroll
            for (int k = 0; k < 4; ++k) {
                const int wk = w0 + k;
                const float mW2 = (wk < 126) ? invS : 0.f;
                const float cW  = (wk < 126) ? 1.f : 0.f;
                const bool  vW  = wk < 127;

                const float xW = A0[k + 2] - 2.f * A0[k + 1] + A0[k];
                local += xW * xW * mW2;
                const float xD = AD2[k] - 2.f * AD[k] + A0[k];
                local += xD * xD * mD2;
                const float xH = AH2[k] - 2.f * AH[k] + A0[k];
                local += xH * xH * mH2;

                const float xDH = ADH[k] - AD[k] - AH[k] + A0[k];
                local += xDH * xDH * (((vD && vH) ? (cD + cH) : 0.f) * invC);
                const float xDW = AD[k + 1] - AD[k] - A0[k + 1] + A0[k];
                local += xDW * xDW * (((vD && vW) ? (cD + cW) : 0.f) * invC);
                const float xHW = AH[k + 1] - AH[k] - A0[k + 1] + A0[k];
                local += xHW * xHW * (((vH && vW) ? (cH + cW) : 0.f) * invC);
            }
        }

        float* rlds = &smem[0][0][0][0];
        const float s = wave_block_reduce_partial(local, rlds, threadIdx.x, 4);
        if (threadIdx.x == 0) regPartial[vb] = s;
    }
}

// ---------------- Kernel 2: D-box + NCC + block reduce ----------------
// Block = (b, h, seg-group). 256 threads = w-pair(64) x 4 segs. Each seg: 8 owned d + 8 halo.
__global__ __launch_bounds__(256) void ncc_d(const unsigned* __restrict__ bufB,
                                             float* __restrict__ nccPartial) {
    const int t = threadIdx.x;
    const int wp = t & 63;             // w-pair index
    const int sg = t >> 6;             // 0..3
    const int b = blockIdx.x >> 9;
    const int h = (blockIdx.x >> 2) & 127;
    const int g = blockIdx.x & 3;
    const int d0 = ((g << 2) + sg) << 3;   // owned d: d0..d0+7
    const float inv_n = 1.0f / 729.0f;

    unsigned win[9][5];
    float2 rs[5];
    #pragma unroll
    for (int f = 0; f < 5; ++f) rs[f] = ZER2;
    float local = 0.f;

    #pragma unroll
    for (int s = 0; s < 16; ++s) {
        const int dd = d0 - 4 + s;
        unsigned x[5];
        if (dd >= 0 && dd < 128) {
            const unsigned* row = bufB + ((b * 128 + dd) * 128 + h) * 320;
            const uint2 a01 = *reinterpret_cast<const uint2*>(row + 2 * wp);
            const uint2 a23 = *reinterpret_cast<const uint2*>(row + 128 + 2 * wp);
            x[0] = a01.x; x[1] = a01.y; x[2] = a23.x; x[3] = a23.y;
            x[4] = row[256 + wp];
        } else {
            #pragma unroll
            for (int f = 0; f < 5; ++f) x[f] = 0u;
        }
        #pragma unroll
        for (int f = 0; f < 5; ++f) {
            if (s >= 9) {
                const float2 o = unpack_bf2(win[s % 9][f]);
                rs[f].x -= o.x; rs[f].y -= o.y;
            }
            const float2 nv = unpack_bf2(x[f]);
            rs[f].x += nv.x; rs[f].y += nv.y;
            win[s % 9][f] = x[f];
        }
        if (s >= 8) {
            const float uix = rs[0].x * inv_n, uiy = rs[0].y * inv_n;
            const float ujx = rs[1].x * inv_n, ujy = rs[1].y * inv_n;
            const float i2x = rs[2].x * inv_n - uix * uix;
            const float i2y = rs[2].y * inv_n - uiy * uiy;
            const float j2x = rs[3].x * inv_n - ujx * ujx;
            const float j2y = rs[3].y * inv_n - ujy * ujy;
            const float ijx = rs[4].x * inv_n - uix * ujx;
            const float ijy = rs[4].y * inv_n - uiy * ujy;
            local += ijx * ijx / (i2x * j2x + 1e-5f)
                   + ijy * ijy / (i2y * j2y + 1e-5f);
        }
    }

    __shared__ float lds[4];
    const float s = wave_block_reduce_partial(local, lds, t, 4);
    if (t == 0) nccPartial[blockIdx.x] = s;
}

// ---------------- Finalize ----------------
__global__ void finalize(const float* __restrict__ nccPartial, const float* __restrict__ regPartial,
                         float* __restrict__ out) {
    __shared__ float sdata[256];
    const int t = threadIdx.x;
    float a = 0.f;
    for (int i = t; i < 1024; i += 256) a += nccPartial[i];
    sdata[t] = a; __syncthreads();
    for (int s = 128; s > 0; s >>= 1) { if (t < s) sdata[t] += sdata[t + s]; __syncthreads(); }
    const float nccSum = sdata[0];
    __syncthreads();
    float bsum = 0.f;
    for (int i = t; i < 3072; i += 256) bsum += regPartial[i];
    sdata[t] = bsum; __syncthreads();
    for (int s = 128; s > 0; s >>= 1) { if (t < s) sdata[t] += sdata[t + s]; __syncthreads(); }
    if (t == 0) {
        const float reg = sdata[0];
        const float sim = -nccSum / (float)V;
        out[0] = sim + 0.01f * reg;
        out[1] = sim;
        out[2] = reg;
    }
}

extern "C" void kernel_launch(void* const* d_in, const int* in_sizes, int n_in,
                              void* d_out, int out_size, void* d_ws, size_t ws_size,
                              hipStream_t stream) {
    const float* warped = (const float*)d_in[0];
    const float* fixedv = (const float*)d_in[1];
    const float* flow   = (const float*)d_in[2];
    float* out = (float*)d_out;
    float* ws  = (float*)d_ws;

    // ws layout (floats): [0,1024) nccPartial | [1024,4096) regPartial | pad |
    //                     [16384, ...) bufB packed bf16 (2*128^3*5*2B ~= 42 MB)
    float* nccPartial = ws;
    float* regPartial = ws + 1024;
    unsigned* bufB = (unsigned*)(ws + 16384);

    // 4096 blocks: idx%4==0 -> ncc_wh (1024 blocks = 4096 waves), else bending (3072)
    wh_bend<<<dim3(4096), dim3(256), 0, stream>>>(warped, fixedv, flow, bufB, regPartial);
    // 1024 blocks = (b, h, seg-group); 256 threads = w-pair x 4 d-segments
    ncc_d<<<dim3(1024), dim3(256), 0, stream>>>(bufB, nccPartial);
    finalize<<<dim3(1), dim3(256), 0, stream>>>(nccPartial, regPartial, out);
}

// Round 8
// 66.005 us; speedup vs baseline: 1.3264x; 1.3264x over previous
//
#include <hip/hip_runtime.h>

// RegistrationLoss: sim = -mean(NCC_9x9x9(warped, fixed)), reg = bending energy of flow,
// total = sim + 0.01*reg. Inputs f32: warped[2,1,128,128,128], fixed same, flow[2,3,128,128,128].
// Output: 3 floats [total, sim, reg].
//
// Round-8 structure (revert of R7's failed block-type fusion — mixing wh blocks with
// bending blocks cut wh residency 4x and stretched it to 88us):
//   ncc_wh: 2-step-ahead global prefetch (HBM lat ~500-900cy > 1 step of work),
//           double-buffered wave-private zero-padded LDS row (no barriers),
//           5 shifted ds_read_b64 views, W-box, H-box f32 register ring,
//           bufB packed bf16 (42 MB), uint4+dword stores.
//   ncc_d:  D-box register ring over 16 d-segments, 1-step register prefetch,
//           uint4+dword loads, NCC + block reduce; f32 accum.
//   bending: branch-free float4 kernel (R3 version).
// bufB row layout (per (b,d,h), 320 unsigned = 1280 B):
//   [0,256): uint4{bf2(f0),bf2(f1),bf2(f2),bf2(f3)} per w-pair at 4*wp
//   [256,320): bf2(f4) dword per w-pair
// Lessons kept: no min-waves launch_bounds (R4: VGPR cap -> spill); no per-LANE
// conditional loads (R5: exec-mask serialization) — validity guards are wave-uniform.

#define DIM 128
#define V   4194304L      // 2*128^3
#define NVOL6 12582912L   // 6*128^3

#define ZER2 make_float2(0.f, 0.f)

__device__ __forceinline__ unsigned pack_bf2(float2 v) {
    unsigned ax = __float_as_uint(v.x), ay = __float_as_uint(v.y);
    ax = ax + 0x7fffu + ((ax >> 16) & 1u);      // round-to-nearest-even
    ay = ay + 0x7fffu + ((ay >> 16) & 1u);
    return (ax >> 16) | (ay & 0xffff0000u);
}
__device__ __forceinline__ float2 unpack_bf2(unsigned u) {
    return make_float2(__uint_as_float(u << 16), __uint_as_float(u & 0xffff0000u));
}

__device__ __forceinline__ float wave_block_reduce_partial(float local, float* lds, int t, int nwaves) {
    #pragma unroll
    for (int off = 32; off > 0; off >>= 1) local += __shfl_down(local, off, 64);
    if ((t & 63) == 0) lds[t >> 6] = local;
    __syncthreads();
    float s = 0.f;
    if (t == 0) {
        for (int i = 0; i < nwaves; ++i) s += lds[i];
    }
    return s; // valid on t==0 only
}

// ---------------- Kernel 1: products + W-box + H-box -> bufB (packed bf16) ----------------
// Wave = (b, d, h-chunk of 8). Lane owns w-pair. 16 h-steps, 9-deep H register ring.
__global__ __launch_bounds__(256) void ncc_wh(const float* __restrict__ I,
                                              const float* __restrict__ J,
                                              unsigned* __restrict__ bufB) {
    __shared__ float smem[4][2][2][136];  // [wave][slot][src][4 pad | 128 | 4 pad]

    const int lane = threadIdx.x & 63;
    const int wv   = threadIdx.x >> 6;
    const int wid  = (blockIdx.x << 2) + wv;   // [0, 4096)
    const int e = wid & 15;           // h-chunk
    const int d = (wid >> 4) & 127;
    const int b = wid >> 11;
    const int h0 = e << 3;
    const int w0 = lane << 1;
    const int sliceBase = (b * 128 + d) * 16384;

    // zero the pads of both slots/sources once (lanes 0..3)
    if (lane < 4) {
        #pragma unroll
        for (int sl = 0; sl < 2; ++sl)
            #pragma unroll
            for (int sc = 0; sc < 2; ++sc) {
                smem[wv][sl][sc][lane] = 0.f;
                smem[wv][sl][sc][132 + lane] = 0.f;
            }
    }

    float2 win[9][5];
    float2 hs[5];
    #pragma unroll
    for (int f = 0; f < 5; ++f) hs[f] = ZER2;

    // prologue: row h0-4 -> slot 0; prefetch h0-3 (na) and h0-2 (ma)
    {
        const int h = h0 - 4;
        float2 ca = ZER2, cb = ZER2;
        if ((unsigned)h < 128u) {      // wave-uniform guard
            ca = *reinterpret_cast<const float2*>(I + sliceBase + h * 128 + w0);
            cb = *reinterpret_cast<const float2*>(J + sliceBase + h * 128 + w0);
        }
        *reinterpret_cast<float2*>(&smem[wv][0][0][4 + w0]) = ca;
        *reinterpret_cast<float2*>(&smem[wv][0][1][4 + w0]) = cb;
    }
    float2 na = ZER2, nb = ZER2, ma = ZER2, mb = ZER2;
    {
        const int h = h0 - 3;
        if ((unsigned)h < 128u) {
            na = *reinterpret_cast<const float2*>(I + sliceBase + h * 128 + w0);
            nb = *reinterpret_cast<const float2*>(J + sliceBase + h * 128 + w0);
        }
    }
    {
        const int h = h0 - 2;
        if ((unsigned)h < 128u) {
            ma = *reinterpret_cast<const float2*>(I + sliceBase + h * 128 + w0);
            mb = *reinterpret_cast<const float2*>(J + sliceBase + h * 128 + w0);
        }
    }

    #pragma unroll
    for (int s = 0; s < 16; ++s) {
        const int slot = s & 1, nslot = slot ^ 1;
        // stage row s+1 (na) into the other slot; rotate 2-deep prefetch pipeline
        *reinterpret_cast<float2*>(&smem[wv][nslot][0][4 + w0]) = na;
        *reinterpret_cast<float2*>(&smem[wv][nslot][1][4 + w0]) = nb;
        na = ma; nb = mb;
        {
            const int h = h0 - 1 + s;          // row for step s+3... (2 ahead of stage)
            if ((unsigned)h < 128u) {
                ma = *reinterpret_cast<const float2*>(I + sliceBase + h * 128 + w0);
                mb = *reinterpret_cast<const float2*>(J + sliceBase + h * 128 + w0);
            } else {
                ma = ZER2; mb = ZER2;
            }
        }

        // 5 shifted views of current row (written at step s-1, slot = s&1)
        float2 iv[5], jv[5];
        #pragma unroll
        for (int o = 0; o < 5; ++o) {
            iv[o] = *reinterpret_cast<const float2*>(&smem[wv][slot][0][w0 + 2 * o]);
            jv[o] = *reinterpret_cast<const float2*>(&smem[wv][slot][1][w0 + 2 * o]);
        }

        float2 v[5][5];
        #pragma unroll
        for (int o = 0; o < 5; ++o) {
            v[0][o] = iv[o];
            v[1][o] = jv[o];
            v[2][o] = make_float2(iv[o].x * iv[o].x, iv[o].y * iv[o].y);
            v[3][o] = make_float2(jv[o].x * jv[o].x, jv[o].y * jv[o].y);
            v[4][o] = make_float2(iv[o].x * jv[o].x, iv[o].y * jv[o].y);
        }

        #pragma unroll
        for (int f = 0; f < 5; ++f) {
            const float core = v[f][1].x + v[f][1].y + v[f][2].x + v[f][2].y
                             + v[f][3].x + v[f][3].y;
            float2 wb;
            wb.x = core + v[f][0].x + v[f][0].y + v[f][4].x;   // window w-4..w+4
            wb.y = core + v[f][0].y + v[f][4].x + v[f][4].y;   // window w-3..w+5
            if (s >= 9) { hs[f].x -= win[s % 9][f].x; hs[f].y -= win[s % 9][f].y; }
            hs[f].x += wb.x; hs[f].y += wb.y;
            win[s % 9][f] = wb;
        }

        if (s >= 8) {
            const int h_out = h0 + s - 8;
            unsigned* row = bufB + ((b * 128 + d) * 128 + h_out) * 320;
            const uint4 pk = make_uint4(pack_bf2(hs[0]), pack_bf2(hs[1]),
                                        pack_bf2(hs[2]), pack_bf2(hs[3]));
            *reinterpret_cast<uint4*>(row + 4 * lane) = pk;
            row[256 + lane] = pack_bf2(hs[4]);
        }
    }
}

// ---------------- Kernel 2: D-box + NCC + block reduce ----------------
// Block = (b, h, seg-group). 256 threads = w-pair(64) x 4 segs (sg wave-uniform).
// Each seg: 8 owned d + 8 halo. 1-step register prefetch of the 20 B row slice.
__global__ __launch_bounds__(256) void ncc_d(const unsigned* __restrict__ bufB,
                                             float* __restrict__ nccPartial) {
    const int t = threadIdx.x;
    const int wp = t & 63;             // w-pair index
    const int sg = t >> 6;             // 0..3 (wave-uniform)
    const int b = blockIdx.x >> 9;
    const int h = (blockIdx.x >> 2) & 127;
    const int g = blockIdx.x & 3;
    const int d0 = ((g << 2) + sg) << 3;   // owned d: d0..d0+7
    const float inv_n = 1.0f / 729.0f;

    unsigned win[9][5];
    float2 rs[5];
    #pragma unroll
    for (int f = 0; f < 5; ++f) rs[f] = ZER2;
    float local = 0.f;

    // prefetch step 0 (dd = d0-4)
    uint4 nx = make_uint4(0u, 0u, 0u, 0u);
    unsigned nx4 = 0u;
    {
        const int dd = d0 - 4;
        if ((unsigned)dd < 128u) {
            const unsigned* row = bufB + ((b * 128 + dd) * 128 + h) * 320;
            nx = *reinterpret_cast<const uint4*>(row + 4 * wp);
            nx4 = row[256 + wp];
        }
    }

    #pragma unroll
    for (int s = 0; s < 16; ++s) {
        const uint4 cx = nx;
        const unsigned cx4 = nx4;
        if (s < 15) {
            const int dd = d0 - 3 + s;
            if ((unsigned)dd < 128u) {
                const unsigned* row = bufB + ((b * 128 + dd) * 128 + h) * 320;
                nx = *reinterpret_cast<const uint4*>(row + 4 * wp);
                nx4 = row[256 + wp];
            } else {
                nx = make_uint4(0u, 0u, 0u, 0u); nx4 = 0u;
            }
        }

        const unsigned x[5] = {cx.x, cx.y, cx.z, cx.w, cx4};
        #pragma unroll
        for (int f = 0; f < 5; ++f) {
            if (s >= 9) {
                const float2 o = unpack_bf2(win[s % 9][f]);
                rs[f].x -= o.x; rs[f].y -= o.y;
            }
            const float2 nv = unpack_bf2(x[f]);
            rs[f].x += nv.x; rs[f].y += nv.y;
            win[s % 9][f] = x[f];
        }
        if (s >= 8) {
            const float uix = rs[0].x * inv_n, uiy = rs[0].y * inv_n;
            const float ujx = rs[1].x * inv_n, ujy = rs[1].y * inv_n;
            const float i2x = rs[2].x * inv_n - uix * uix;
            const float i2y = rs[2].y * inv_n - uiy * uiy;
            const float j2x = rs[3].x * inv_n - ujx * ujx;
            const float j2y = rs[3].y * inv_n - ujy * ujy;
            const float ijx = rs[4].x * inv_n - uix * ujx;
            const float ijy = rs[4].y * inv_n - uiy * ujy;
            local += ijx * ijx / (i2x * j2x + 1e-5f)
                   + ijy * ijy / (i2y * j2y + 1e-5f);
        }
    }

    __shared__ float lds[4];
    const float s = wave_block_reduce_partial(local, lds, t, 4);
    if (t == 0) nccPartial[blockIdx.x] = s;
}

// ---------------- Bending energy: branch-free, float4-vectorized ----------------
__global__ __launch_bounds__(256) void bending(const float* __restrict__ F,
                                               float* __restrict__ regPartial) {
    const float invS = 1.0f / 12386304.0f;   // 6*126*128*128  (i==j)
    const float invC = 1.0f / 12289536.0f;   // 6*127*126*128  (i!=j, both orderings)

    const int tid = blockIdx.x * 256 + threadIdx.x;     // [0, 3145728)
    const long e = (long)tid << 2;                       // element base (multiple of 4)
    const int r = (int)(e & 2097151);
    const int d = r >> 14;
    const int h = (r >> 7) & 127;
    const int w0 = r & 127;                              // 0,4,...,124

    const float* p = F + e;
    const int off4 = (w0 < 124) ? 4 : 0;                 // clamped w-tail offset
    const int oD  = (d < 127) ? 16384 : 0;
    const int oD2 = (d < 126) ? 32768 : 0;
    const int oH  = (h < 127) ? 128 : 0;
    const int oH2 = (h < 126) ? 256 : 0;

    const float4 a0  = *reinterpret_cast<const float4*>(p);
    const float2 s45 = *reinterpret_cast<const float2*>(p + off4);
    const float4 aD  = *reinterpret_cast<const float4*>(p + oD);
    const float  sD4 = (p + oD)[off4];
    const float4 aD2 = *reinterpret_cast<const float4*>(p + oD2);
    const float4 aH  = *reinterpret_cast<const float4*>(p + oH);
    const float  sH4 = (p + oH)[off4];
    const float4 aH2 = *reinterpret_cast<const float4*>(p + oH2);
    const float4 aDH = *reinterpret_cast<const float4*>(p + oD + oH);

    const float A0[6] = {a0.x, a0.y, a0.z, a0.w, s45.x, s45.y};
    const float AD[5] = {aD.x, aD.y, aD.z, aD.w, sD4};
    const float AH[5] = {aH.x, aH.y, aH.z, aH.w, sH4};
    const float AD2[4] = {aD2.x, aD2.y, aD2.z, aD2.w};
    const float AH2[4] = {aH2.x, aH2.y, aH2.z, aH2.w};
    const float ADH[4] = {aDH.x, aDH.y, aDH.z, aDH.w};

    const float mD2 = (d < 126) ? invS : 0.f;
    const float mH2 = (h < 126) ? invS : 0.f;
    const float cD  = (d < 126) ? 1.f : 0.f;
    const float cH  = (h < 126) ? 1.f : 0.f;
    const bool  vD  = d < 127, vH = h < 127;

    float local = 0.f;
    #pragma unroll
    for (int k = 0; k < 4; ++k) {
        const int wk = w0 + k;
        const float mW2 = (wk < 126) ? invS : 0.f;
        const float cW  = (wk < 126) ? 1.f : 0.f;
        const bool  vW  = wk < 127;

        const float xW = A0[k + 2] - 2.f * A0[k + 1] + A0[k];
        local += xW * xW * mW2;
        const float xD = AD2[k] - 2.f * AD[k] + A0[k];
        local += xD * xD * mD2;
        const float xH = AH2[k] - 2.f * AH[k] + A0[k];
        local += xH * xH * mH2;

        const float xDH = ADH[k] - AD[k] - AH[k] + A0[k];
        local += xDH * xDH * (((vD && vH) ? (cD + cH) : 0.f) * invC);
        const float xDW = AD[k + 1] - AD[k] - A0[k + 1] + A0[k];
        local += xDW * xDW * (((vD && vW) ? (cD + cW) : 0.f) * invC);
        const float xHW = AH[k + 1] - AH[k] - A0[k + 1] + A0[k];
        local += xHW * xHW * (((vH && vW) ? (cH + cW) : 0.f) * invC);
    }

    __shared__ float lds[4];
    const float s = wave_block_reduce_partial(local, lds, threadIdx.x, 4);
    if (threadIdx.x == 0) regPartial[blockIdx.x] = s;
}

// ---------------- Finalize ----------------
__global__ void finalize(const float* __restrict__ nccPartial, const float* __restrict__ regPartial,
                         float* __restrict__ out) {
    __shared__ float sdata[256];
    const int t = threadIdx.x;
    float a = 0.f;
    for (int i = t; i < 1024; i += 256) a += nccPartial[i];
    sdata[t] = a; __syncthreads();
    for (int s = 128; s > 0; s >>= 1) { if (t < s) sdata[t] += sdata[t + s]; __syncthreads(); }
    const float nccSum = sdata[0];
    __syncthreads();
    float bsum = 0.f;
    for (int i = t; i < 12288; i += 256) bsum += regPartial[i];
    sdata[t] = bsum; __syncthreads();
    for (int s = 128; s > 0; s >>= 1) { if (t < s) sdata[t] += sdata[t + s]; __syncthreads(); }
    if (t == 0) {
        const float reg = sdata[0];
        const float sim = -nccSum / (float)V;
        out[0] = sim + 0.01f * reg;
        out[1] = sim;
        out[2] = reg;
    }
}

extern "C" void kernel_launch(void* const* d_in, const int* in_sizes, int n_in,
                              void* d_out, int out_size, void* d_ws, size_t ws_size,
                              hipStream_t stream) {
    const float* warped = (const float*)d_in[0];
    const float* fixedv = (const float*)d_in[1];
    const float* flow   = (const float*)d_in[2];
    float* out = (float*)d_out;
    float* ws  = (float*)d_ws;

    // ws layout (floats): [0,1024) nccPartial | [1024,13312) regPartial | pad |
    //                     [16384, ...) bufB packed bf16 (2*128^3*5*2B ~= 42 MB)
    float* nccPartial = ws;
    float* regPartial = ws + 1024;
    unsigned* bufB = (unsigned*)(ws + 16384);

    // 4096 waves: wave = (b, d, h-chunk of 8)
    ncc_wh<<<dim3(1024), dim3(256), 0, stream>>>(warped, fixedv, bufB);
    // 1024 blocks = (b, h, seg-group); 256 threads = w-pair x 4 d-segments
    ncc_d<<<dim3(1024), dim3(256), 0, stream>>>(bufB, nccPartial);
    bending<<<dim3(12288), dim3(256), 0, stream>>>(flow, regPartial);
    finalize<<<dim3(1), dim3(256), 0, stream>>>(nccPartial, regPartial, out);
}

// Round 9
// 53.533 us; speedup vs baseline: 1.6354x; 1.2330x over previous
//
#include <hip/hip_runtime.h>

// RegistrationLoss: sim = -mean(NCC_9x9x9(warped, fixed)), reg = bending energy of flow,
// total = sim + 0.01*reg. Inputs f32: warped[2,1,128,128,128], fixed same, flow[2,3,128,128,128].
// Output: 3 floats [total, sim, reg].
//
// Round-9 structure:
//   wh_bend: ncc_wh phase (2-deep global prefetch, double-buffered wave-private
//            zero-padded LDS row, 5 shifted ds_read_b64 views, W-box + H-box f32 ring,
//            bufB packed bf16 42 MB) THEN a sequential bending-energy phase
//            (grid-strided 12 float4-iterations/thread). All blocks identical ->
//            no residency asymmetry (R7 lesson: block-TYPE mixing cut wh residency 4x);
//            staggered wave progress lets bending's streaming fill wh's latency bubbles.
//   ncc_d:  D-box register ring over 16 d-segments, 1-step register prefetch,
//           uint4+dword loads, NCC + block reduce; f32 accum.
// bufB row layout (per (b,d,h), 320 unsigned = 1280 B):
//   [0,256): uint4{bf2(f0),bf2(f1),bf2(f2),bf2(f3)} per w-pair at 4*wp
//   [256,320): bf2(f4) dword per w-pair
// Lessons kept: no min-waves launch_bounds (R4: VGPR cap -> spill); no per-LANE
// conditional loads (R5: exec-mask serialization) — validity guards are wave-uniform.

#define DIM 128
#define V   4194304L      // 2*128^3
#define NVOL6 12582912L   // 6*128^3

#define ZER2 make_float2(0.f, 0.f)

__device__ __forceinline__ unsigned pack_bf2(float2 v) {
    unsigned ax = __float_as_uint(v.x), ay = __float_as_uint(v.y);
    ax = ax + 0x7fffu + ((ax >> 16) & 1u);      // round-to-nearest-even
    ay = ay + 0x7fffu + ((ay >> 16) & 1u);
    return (ax >> 16) | (ay & 0xffff0000u);
}
__device__ __forceinline__ float2 unpack_bf2(unsigned u) {
    return make_float2(__uint_as_float(u << 16), __uint_as_float(u & 0xffff0000u));
}

__device__ __forceinline__ float wave_block_reduce_partial(float local, float* lds, int t, int nwaves) {
    #pragma unroll
    for (int off = 32; off > 0; off >>= 1) local += __shfl_down(local, off, 64);
    if ((t & 63) == 0) lds[t >> 6] = local;
    __syncthreads();
    float s = 0.f;
    if (t == 0) {
        for (int i = 0; i < nwaves; ++i) s += lds[i];
    }
    return s; // valid on t==0 only
}

// ---------------- Kernel 1: ncc_wh phase + bending phase ----------------
__global__ __launch_bounds__(256) void wh_bend(const float* __restrict__ I,
                                               const float* __restrict__ J,
                                               const float* __restrict__ F,
                                               unsigned* __restrict__ bufB,
                                               float* __restrict__ regPartial) {
    __shared__ float smem[4][2][2][136];  // [wave][slot][src][4 pad | 128 | 4 pad]

    // ================= phase 1: products + W-box + H-box -> bufB =================
    {
        const int lane = threadIdx.x & 63;
        const int wv   = threadIdx.x >> 6;
        const int wid  = (blockIdx.x << 2) + wv;   // [0, 4096)
        const int e = wid & 15;           // h-chunk
        const int d = (wid >> 4) & 127;
        const int b = wid >> 11;
        const int h0 = e << 3;
        const int w0 = lane << 1;
        const int sliceBase = (b * 128 + d) * 16384;

        // zero the pads of both slots/sources once (lanes 0..3)
        if (lane < 4) {
            #pragma unroll
            for (int sl = 0; sl < 2; ++sl)
                #pragma unroll
                for (int sc = 0; sc < 2; ++sc) {
                    smem[wv][sl][sc][lane] = 0.f;
                    smem[wv][sl][sc][132 + lane] = 0.f;
                }
        }

        float2 win[9][5];
        float2 hs[5];
        #pragma unroll
        for (int f = 0; f < 5; ++f) hs[f] = ZER2;

        // prologue: row h0-4 -> slot 0; prefetch h0-3 (na) and h0-2 (ma)
        {
            const int h = h0 - 4;
            float2 ca = ZER2, cb = ZER2;
            if ((unsigned)h < 128u) {      // wave-uniform guard
                ca = *reinterpret_cast<const float2*>(I + sliceBase + h * 128 + w0);
                cb = *reinterpret_cast<const float2*>(J + sliceBase + h * 128 + w0);
            }
            *reinterpret_cast<float2*>(&smem[wv][0][0][4 + w0]) = ca;
            *reinterpret_cast<float2*>(&smem[wv][0][1][4 + w0]) = cb;
        }
        float2 na = ZER2, nb = ZER2, ma = ZER2, mb = ZER2;
        {
            const int h = h0 - 3;
            if ((unsigned)h < 128u) {
                na = *reinterpret_cast<const float2*>(I + sliceBase + h * 128 + w0);
                nb = *reinterpret_cast<const float2*>(J + sliceBase + h * 128 + w0);
            }
        }
        {
            const int h = h0 - 2;
            if ((unsigned)h < 128u) {
                ma = *reinterpret_cast<const float2*>(I + sliceBase + h * 128 + w0);
                mb = *reinterpret_cast<const float2*>(J + sliceBase + h * 128 + w0);
            }
        }

        #pragma unroll
        for (int s = 0; s < 16; ++s) {
            const int slot = s & 1, nslot = slot ^ 1;
            // stage row s+1 (na) into the other slot; rotate 2-deep prefetch pipeline
            *reinterpret_cast<float2*>(&smem[wv][nslot][0][4 + w0]) = na;
            *reinterpret_cast<float2*>(&smem[wv][nslot][1][4 + w0]) = nb;
            na = ma; nb = mb;
            {
                const int h = h0 - 1 + s;
                if ((unsigned)h < 128u) {
                    ma = *reinterpret_cast<const float2*>(I + sliceBase + h * 128 + w0);
                    mb = *reinterpret_cast<const float2*>(J + sliceBase + h * 128 + w0);
                } else {
                    ma = ZER2; mb = ZER2;
                }
            }

            // 5 shifted views of current row (written at step s-1, slot = s&1)
            float2 iv[5], jv[5];
            #pragma unroll
            for (int o = 0; o < 5; ++o) {
                iv[o] = *reinterpret_cast<const float2*>(&smem[wv][slot][0][w0 + 2 * o]);
                jv[o] = *reinterpret_cast<const float2*>(&smem[wv][slot][1][w0 + 2 * o]);
            }

            float2 v[5][5];
            #pragma unroll
            for (int o = 0; o < 5; ++o) {
                v[0][o] = iv[o];
                v[1][o] = jv[o];
                v[2][o] = make_float2(iv[o].x * iv[o].x, iv[o].y * iv[o].y);
                v[3][o] = make_float2(jv[o].x * jv[o].x, jv[o].y * jv[o].y);
                v[4][o] = make_float2(iv[o].x * jv[o].x, iv[o].y * jv[o].y);
            }

            #pragma unroll
            for (int f = 0; f < 5; ++f) {
                const float core = v[f][1].x + v[f][1].y + v[f][2].x + v[f][2].y
                                 + v[f][3].x + v[f][3].y;
                float2 wb;
                wb.x = core + v[f][0].x + v[f][0].y + v[f][4].x;   // window w-4..w+4
                wb.y = core + v[f][0].y + v[f][4].x + v[f][4].y;   // window w-3..w+5
                if (s >= 9) { hs[f].x -= win[s % 9][f].x; hs[f].y -= win[s % 9][f].y; }
                hs[f].x += wb.x; hs[f].y += wb.y;
                win[s % 9][f] = wb;
            }

            if (s >= 8) {
                const int h_out = h0 + s - 8;
                unsigned* row = bufB + ((b * 128 + d) * 128 + h_out) * 320;
                const uint4 pk = make_uint4(pack_bf2(hs[0]), pack_bf2(hs[1]),
                                            pack_bf2(hs[2]), pack_bf2(hs[3]));
                *reinterpret_cast<uint4*>(row + 4 * lane) = pk;
                row[256 + lane] = pack_bf2(hs[4]);
            }
        }
    }

    // ================= phase 2: bending energy (tail-fill, grid-strided) =================
    {
        const float invS = 1.0f / 12386304.0f;   // 6*126*128*128  (i==j)
        const float invC = 1.0f / 12289536.0f;   // 6*127*126*128  (i!=j, both orderings)
        float local = 0.f;

        #pragma unroll 2
        for (int it = 0; it < 12; ++it) {
            const int tid = (blockIdx.x + it * 1024) * 256 + threadIdx.x;  // [0, 3145728)
            const long e = (long)tid << 2;                                  // element base
            const int r = (int)(e & 2097151);
            const int d = r >> 14;
            const int h = (r >> 7) & 127;
            const int w0 = r & 127;                                         // 0,4,...,124

            const float* p = F + e;
            const int off4 = (w0 < 124) ? 4 : 0;
            const int oD  = (d < 127) ? 16384 : 0;
            const int oD2 = (d < 126) ? 32768 : 0;
            const int oH  = (h < 127) ? 128 : 0;
            const int oH2 = (h < 126) ? 256 : 0;

            const float4 a0  = *reinterpret_cast<const float4*>(p);
            const float2 s45 = *reinterpret_cast<const float2*>(p + off4);
            const float4 aD  = *reinterpret_cast<const float4*>(p + oD);
            const float  sD4 = (p + oD)[off4];
            const float4 aD2 = *reinterpret_cast<const float4*>(p + oD2);
            const float4 aH  = *reinterpret_cast<const float4*>(p + oH);
            const float  sH4 = (p + oH)[off4];
            const float4 aH2 = *reinterpret_cast<const float4*>(p + oH2);
            const float4 aDH = *reinterpret_cast<const float4*>(p + oD + oH);

            const float A0[6] = {a0.x, a0.y, a0.z, a0.w, s45.x, s45.y};
            const float AD[5] = {aD.x, aD.y, aD.z, aD.w, sD4};
            const float AH[5] = {aH.x, aH.y, aH.z, aH.w, sH4};
            const float AD2[4] = {aD2.x, aD2.y, aD2.z, aD2.w};
            const float AH2[4] = {aH2.x, aH2.y, aH2.z, aH2.w};
            const float ADH[4] = {aDH.x, aDH.y, aDH.z, aDH.w};

            const float mD2 = (d < 126) ? invS : 0.f;
            const float mH2 = (h < 126) ? invS : 0.f;
            const float cD  = (d < 126) ? 1.f : 0.f;
            const float cH  = (h < 126) ? 1.f : 0.f;
            const bool  vD  = d < 127, vH = h < 127;

            #pragma unroll
            for (int k = 0; k < 4; ++k) {
                const int wk = w0 + k;
                const float mW2 = (wk < 126) ? invS : 0.f;
                const float cW  = (wk < 126) ? 1.f : 0.f;
                const bool  vW  = wk < 127;

                const float xW = A0[k + 2] - 2.f * A0[k + 1] + A0[k];
                local += xW * xW * mW2;
                const float xD = AD2[k] - 2.f * AD[k] + A0[k];
                local += xD * xD * mD2;
                const float xH = AH2[k] - 2.f * AH[k] + A0[k];
                local += xH * xH * mH2;

                const float xDH = ADH[k] - AD[k] - AH[k] + A0[k];
                local += xDH * xDH * (((vD && vH) ? (cD + cH) : 0.f) * invC);
                const float xDW = AD[k + 1] - AD[k] - A0[k + 1] + A0[k];
                local += xDW * xDW * (((vD && vW) ? (cD + cW) : 0.f) * invC);
                const float xHW = AH[k + 1] - AH[k] - A0[k + 1] + A0[k];
                local += xHW * xHW * (((vH && vW) ? (cH + cW) : 0.f) * invC);
            }
        }

        __shared__ float rl[4];
        const float s = wave_block_reduce_partial(local, rl, threadIdx.x, 4);
        if (threadIdx.x == 0) regPartial[blockIdx.x] = s;
    }
}

// ---------------- Kernel 2: D-box + NCC + block reduce ----------------
// Block = (b, h, seg-group). 256 threads = w-pair(64) x 4 segs (sg wave-uniform).
// Each seg: 8 owned d + 8 halo. 1-step register prefetch of the 20 B row slice.
__global__ __launch_bounds__(256) void ncc_d(const unsigned* __restrict__ bufB,
                                             float* __restrict__ nccPartial) {
    const int t = threadIdx.x;
    const int wp = t & 63;             // w-pair index
    const int sg = t >> 6;             // 0..3 (wave-uniform)
    const int b = blockIdx.x >> 9;
    const int h = (blockIdx.x >> 2) & 127;
    const int g = blockIdx.x & 3;
    const int d0 = ((g << 2) + sg) << 3;   // owned d: d0..d0+7
    const float inv_n = 1.0f / 729.0f;

    unsigned win[9][5];
    float2 rs[5];
    #pragma unroll
    for (int f = 0; f < 5; ++f) rs[f] = ZER2;
    float local = 0.f;

    // prefetch step 0 (dd = d0-4)
    uint4 nx = make_uint4(0u, 0u, 0u, 0u);
    unsigned nx4 = 0u;
    {
        const int dd = d0 - 4;
        if ((unsigned)dd < 128u) {
            const unsigned* row = bufB + ((b * 128 + dd) * 128 + h) * 320;
            nx = *reinterpret_cast<const uint4*>(row + 4 * wp);
            nx4 = row[256 + wp];
        }
    }

    #pragma unroll
    for (int s = 0; s < 16; ++s) {
        const uint4 cx = nx;
        const unsigned cx4 = nx4;
        if (s < 15) {
            const int dd = d0 - 3 + s;
            if ((unsigned)dd < 128u) {
                const unsigned* row = bufB + ((b * 128 + dd) * 128 + h) * 320;
                nx = *reinterpret_cast<const uint4*>(row + 4 * wp);
                nx4 = row[256 + wp];
            } else {
                nx = make_uint4(0u, 0u, 0u, 0u); nx4 = 0u;
            }
        }

        const unsigned x[5] = {cx.x, cx.y, cx.z, cx.w, cx4};
        #pragma unroll
        for (int f = 0; f < 5; ++f) {
            if (s >= 9) {
                const float2 o = unpack_bf2(win[s % 9][f]);
                rs[f].x -= o.x; rs[f].y -= o.y;
            }
            const float2 nv = unpack_bf2(x[f]);
            rs[f].x += nv.x; rs[f].y += nv.y;
            win[s % 9][f] = x[f];
        }
        if (s >= 8) {
            const float uix = rs[0].x * inv_n, uiy = rs[0].y * inv_n;
            const float ujx = rs[1].x * inv_n, ujy = rs[1].y * inv_n;
            const float i2x = rs[2].x * inv_n - uix * uix;
            const float i2y = rs[2].y * inv_n - uiy * uiy;
            const float j2x = rs[3].x * inv_n - ujx * ujx;
            const float j2y = rs[3].y * inv_n - ujy * ujy;
            const float ijx = rs[4].x * inv_n - uix * ujx;
            const float ijy = rs[4].y * inv_n - uiy * ujy;
            local += ijx * ijx / (i2x * j2x + 1e-5f)
                   + ijy * ijy / (i2y * j2y + 1e-5f);
        }
    }

    __shared__ float lds[4];
    const float s = wave_block_reduce_partial(local, lds, t, 4);
    if (t == 0) nccPartial[blockIdx.x] = s;
}

// ---------------- Finalize ----------------
__global__ void finalize(const float* __restrict__ nccPartial, const float* __restrict__ regPartial,
                         float* __restrict__ out) {
    __shared__ float sdata[256];
    const int t = threadIdx.x;
    float a = 0.f;
    for (int i = t; i < 1024; i += 256) a += nccPartial[i];
    sdata[t] = a; __syncthreads();
    for (int s = 128; s > 0; s >>= 1) { if (t < s) sdata[t] += sdata[t + s]; __syncthreads(); }
    const float nccSum = sdata[0];
    __syncthreads();
    float bsum = 0.f;
    for (int i = t; i < 1024; i += 256) bsum += regPartial[i];
    sdata[t] = bsum; __syncthreads();
    for (int s = 128; s > 0; s >>= 1) { if (t < s) sdata[t] += sdata[t + s]; __syncthreads(); }
    if (t == 0) {
        const float reg = sdata[0];
        const float sim = -nccSum / (float)V;
        out[0] = sim + 0.01f * reg;
        out[1] = sim;
        out[2] = reg;
    }
}

extern "C" void kernel_launch(void* const* d_in, const int* in_sizes, int n_in,
                              void* d_out, int out_size, void* d_ws, size_t ws_size,
                              hipStream_t stream) {
    const float* warped = (const float*)d_in[0];
    const float* fixedv = (const float*)d_in[1];
    const float* flow   = (const float*)d_in[2];
    float* out = (float*)d_out;
    float* ws  = (float*)d_ws;

    // ws layout (floats): [0,1024) nccPartial | [1024,2048) regPartial | pad |
    //                     [16384, ...) bufB packed bf16 (2*128^3*5*2B ~= 42 MB)
    float* nccPartial = ws;
    float* regPartial = ws + 1024;
    unsigned* bufB = (unsigned*)(ws + 16384);

    // 1024 blocks = 4096 wh-waves (wave = (b, d, h-chunk of 8)) + bending tail-fill
    wh_bend<<<dim3(1024), dim3(256), 0, stream>>>(warped, fixedv, flow, bufB, regPartial);
    // 1024 blocks = (b, h, seg-group); 256 threads = w-pair x 4 d-segments
    ncc_d<<<dim3(1024), dim3(256), 0, stream>>>(bufB, nccPartial);
    finalize<<<dim3(1), dim3(256), 0, stream>>>(nccPartial, regPartial, out);
}